// Round 7
// baseline (2394.978 us; speedup 1.0000x reference)
//
#include <hip/hip_runtime.h>

typedef short short8  __attribute__((ext_vector_type(8)));
typedef short short4v __attribute__((ext_vector_type(4)));
typedef float f32x4   __attribute__((ext_vector_type(4)));

#define MFMA_BF16(A,B,C) __builtin_amdgcn_mfma_f32_16x16x32_bf16((A),(B),(C),0,0,0)

__device__ __forceinline__ short bf16bits(float f){
  return (short)__builtin_bit_cast(unsigned short, static_cast<__bf16>(f));
}

// exp(s*0.125 - 8) = 2^(s*0.125*log2e - 8*log2e), one v_fma + v_exp
#define EXP_SCORE(s) __builtin_amdgcn_exp2f(__builtin_fmaf((s), 0.18033688011112042f, -11.541560327111707f))

// ---------------- fused preprocessing ----------------
// blocks [0,220): mask preprocessing  (region_masks -> allowed bits)
// blocks [220,988): K/V repack to bf16 in IDENTITY-LANE fragment order:
// each MFMA fragment chunk is 1KB = 64 lanes x 16B with lane l's 16B at
// offset l*16 (conflict-free linear ds_read_b128 / fully-coalesced
// global_load_dwordx4 by construction).
//   K  chunk (t,f):  lane = Qd*16 + ck   holds K[key=t*16+ck][d=f*32+Qd*8+j]
//   V^T chunk (kc,m): lane = Qv*16 + cv  holds V[key=kc*32+Qv*8+jv][d=m*16+cv]
__global__ __launch_bounds__(256) void prep_kernel(const float* __restrict__ rm,
                                                   const float* __restrict__ k,
                                                   const float* __restrict__ v,
                                                   const float* __restrict__ rk,
                                                   const float* __restrict__ rv,
                                                   unsigned* __restrict__ allowed,
                                                   unsigned short* __restrict__ Kb,
                                                   unsigned short* __restrict__ VT){
  const int bid = blockIdx.x;
  if (bid < 220){
    int s = bid*256 + threadIdx.x;
    if (s >= 56320) return;
    int t = s / 3520;
    int rem = s - t*3520;
    int i = rem / 80;
    int j = rem - i*80;
    int y = 2*i, x = 2*j;
    bool bin[2];
    #pragma unroll
    for (int r=0;r<2;r++){
      const float* base = rm + (size_t)r*121*88*160;
      float acc;
      if (t == 0){
        const float* p0 = base + (size_t)(0*88 + y)*160 + x;
        acc = 0.25f*(p0[0]+p0[1]+p0[160]+p0[161]);
      } else {
        const float* pa = base + (size_t)((8*t-4)*88 + y)*160 + x;
        const float* pb = base + (size_t)((8*t-3)*88 + y)*160 + x;
        acc = 0.125f*(pa[0]+pa[1]+pa[160]+pa[161] + pb[0]+pb[1]+pb[160]+pb[161]);
      }
      bin[r] = acc > 0.5f;
    }
    unsigned bits = (bin[0]||bin[1]) ? 0u : 1u;
    if (bin[0]) bits |= 2u;
    if (bin[1]) bits |= 4u;
    allowed[s] = bits;
  } else {
    int idx = (bid-220)*256 + threadIdx.x;   // over 3*128*8*64 = 196608
    if (idx >= 3*128*8*64) return;
    int d   = idx & 63;
    int h   = (idx >> 6) & 7;
    int p   = (idx >> 9) & 127;
    int seg = idx >> 16;
    int low = idx & 65535;                   // (p*8+h)*64+d
    float kv_, vv_;
    if (seg == 0){ kv_ = k[low];                          vv_ = v[low]; }
    else         { kv_ = rk[(size_t)(seg-1)*65536 + low]; vv_ = rv[(size_t)(seg-1)*65536 + low]; }
    const int kk = seg*128 + p;              // key index within head, 0..383
    // K: chunk (t=kk>>4, f=d>>5), lane = ((d>>3)&3)*16 + (kk&15), elem j=d&7
    Kb[(size_t)h*24576 + ((kk>>4)*2 + (d>>5))*512
       + ((((d>>3)&3)*16) + (kk&15))*8 + (d&7)] = (unsigned short)bf16bits(kv_);
    // V^T: chunk (kc=kk>>5, m=d>>4), lane = ((kk>>3)&3)*16 + (d&15), elem jv=kk&7
    VT[(size_t)h*24576 + ((kk>>5)*4 + (d>>4))*512
       + ((((kk>>3)&3)*16) + (d&15))*8 + (kk&7)] = (unsigned short)bf16bits(vv_);
  }
}

// ---------------- fused regional+base attention ----------------
// 512 threads (8 waves) per (head, 256-query chunk).
// K (48KB) staged in LDS once (linear memcpy; permutation done in prep).
// V fragments are read DIRECTLY from L2 (VT = 768KB, L2-resident; each
// fragment load is a fully-coalesced 1KB global_load_dwordx4) — dropping
// Vs cuts LDS to 48+32 = 80KB -> 2 blocks/CU -> 4 waves/SIMD.
// Hot-loop ds_read_b128 is lane*16 linear -> conflict-free. Each wave owns
// 32 queries (sets A/B sharing every K/V fragment read). 6 phases of
// {4 score tiles -> unnormalized exp2(s) -> P chunks in LDS; 2 PV chunks}.
// #pragma unroll 1 on the phase loop: rounds 3-6 fully flattened all 6
// phases into one scheduling region; the scheduler hoisted dozens of loads,
// peak pressure blew past the 128-VGPR target and the allocator spilled
// ~37 f32/thread (+133MB scratch WRITE_SIZE, constant across rounds 3-6).
// Bounding the scope to one phase keeps steady-state ~110 regs -> no spill.
__global__ __launch_bounds__(512)
void attn_kernel(const float* __restrict__ q,
                 const unsigned* __restrict__ allowed,
                 const unsigned short* __restrict__ Kb,
                 const unsigned short* __restrict__ VT,
                 float* __restrict__ out){
  const int h    = blockIdx.y;
  const int wave = threadIdx.x >> 6;
  const int lane = threadIdx.x & 63;
  const int c    = lane & 15;        // query col within set / fragment row
  const int Q    = lane >> 4;        // quad

  __shared__ __align__(16) char Ks[49152];   // 24 tiles x 2 frags x 1KB
  __shared__ __align__(16) char Ps[32768];   // 8 waves x 2 sets x 2KB (phase-local)

  const int sA = blockIdx.x*256 + wave*32 + c;
  const int sB = sA + 16;

  // ---- stage K: issue the 6 loads first (48 in-flight regs max), q loads
  //      and bf16 conversion overlap the latency; stores land before barrier
  const char* kg = (const char*)Kb + (size_t)h*49152;
  short8 st0 = *(const short8*)(kg + wave*6144 + 0*1024 + lane*16);
  short8 st1 = *(const short8*)(kg + wave*6144 + 1*1024 + lane*16);
  short8 st2 = *(const short8*)(kg + wave*6144 + 2*1024 + lane*16);
  short8 st3 = *(const short8*)(kg + wave*6144 + 3*1024 + lane*16);
  short8 st4 = *(const short8*)(kg + wave*6144 + 4*1024 + lane*16);
  short8 st5 = *(const short8*)(kg + wave*6144 + 5*1024 + lane*16);

  // ---- q load -> bf16 frags immediately (only 8 regs live past here)
  const unsigned abA = allowed[sA], abB = allowed[sB];
  const float* qpA = q + ((size_t)sA*8 + h)*64 + Q*8;
  const float* qpB = q + ((size_t)sB*8 + h)*64 + Q*8;
  f32x4 qA0 = *(const f32x4*)(qpA);
  f32x4 qA1 = *(const f32x4*)(qpA+4);
  f32x4 qA2 = *(const f32x4*)(qpA+32);
  f32x4 qA3 = *(const f32x4*)(qpA+36);
  f32x4 qB0 = *(const f32x4*)(qpB);
  f32x4 qB1 = *(const f32x4*)(qpB+4);
  f32x4 qB2 = *(const f32x4*)(qpB+32);
  f32x4 qB3 = *(const f32x4*)(qpB+36);
  short8 fA0, fA1, fB0, fB1;
  #pragma unroll
  for (int j=0;j<4;j++){
    fA0[j] = bf16bits(qA0[j]); fA0[4+j] = bf16bits(qA1[j]);
    fA1[j] = bf16bits(qA2[j]); fA1[4+j] = bf16bits(qA3[j]);
    fB0[j] = bf16bits(qB0[j]); fB0[4+j] = bf16bits(qB1[j]);
    fB1[j] = bf16bits(qB2[j]); fB1[4+j] = bf16bits(qB3[j]);
  }

  // ---- K -> LDS (pure linear, conflict-free)
  *(short8*)(Ks + wave*6144 + 0*1024 + lane*16) = st0;
  *(short8*)(Ks + wave*6144 + 1*1024 + lane*16) = st1;
  *(short8*)(Ks + wave*6144 + 2*1024 + lane*16) = st2;
  *(short8*)(Ks + wave*6144 + 3*1024 + lane*16) = st3;
  *(short8*)(Ks + wave*6144 + 4*1024 + lane*16) = st4;
  *(short8*)(Ks + wave*6144 + 5*1024 + lane*16) = st5;

  __syncthreads();   // staged K visible to all waves

  // ---- identity-lane fragment bases (linear, conflict-free)
  const char* kfb = Ks + lane*16;            // + (t*2+f)*1024
  const char* vgf = (const char*)VT + (size_t)h*49152 + lane*16;  // global V frags
  char*       pwb = Ps + wave*4096 + (Q>>1)*256 + c*16 + (Q&1)*8; // + (i>>1)*1024 + (i&1)*512 (+2048 set B)
  const char* prb = Ps + wave*4096 + lane*16;                     // + klp*1024 (+2048 set B)

  const float amA1 = (abA>>1)&1u ? 1.f : 0.f;
  const float amA2 = (abA>>2)&1u ? 1.f : 0.f;
  const float amB1 = (abB>>1)&1u ? 1.f : 0.f;
  const float amB2 = (abB>>2)&1u ? 1.f : 0.f;

  float lbA=0.f, lrA=0.f, lbB=0.f, lrB=0.f;
  f32x4 aA0[4], aA1[4], aB0[4], aB1[4];
  #pragma unroll
  for (int m=0;m<4;m++){
    aA0[m]=(f32x4){0,0,0,0}; aA1[m]=(f32x4){0,0,0,0};
    aB0[m]=(f32x4){0,0,0,0}; aB1[m]=(f32x4){0,0,0,0};
  }

  #pragma unroll 1
  for (int ph=0; ph<6; ++ph){
    const float aAm = (ph<2) ? 1.f : ((ph<4)? amA1 : amA2);
    const float aBm = (ph<2) ? 1.f : ((ph<4)? amB1 : amB2);
    // ---- 4 score tiles (64 keys) -> unnormalized exp2 -> P chunks
    #pragma unroll
    for (int i=0;i<4;i++){
      const int t = ph*4 + i;
      short8 kf0 = *(const short8*)(kfb + (t*2  )*1024);
      short8 kf1 = *(const short8*)(kfb + (t*2+1)*1024);
      f32x4 s4A = {0,0,0,0}; s4A = MFMA_BF16(kf0,fA0,s4A); s4A = MFMA_BF16(kf1,fA1,s4A);
      f32x4 s4B = {0,0,0,0}; s4B = MFMA_BF16(kf0,fB0,s4B); s4B = MFMA_BF16(kf1,fB1,s4B);
      short4v pA, pB;
      if (ph < 2){
        #pragma unroll
        for (int r=0;r<4;r++){
          float eA = EXP_SCORE(s4A[r]); lbA += eA; pA[r] = bf16bits(eA);
          float eB = EXP_SCORE(s4B[r]); lbB += eB; pB[r] = bf16bits(eB);
        }
      } else {
        #pragma unroll
        for (int r=0;r<4;r++){
          float eA = aAm*EXP_SCORE(s4A[r]); lrA += eA; pA[r] = bf16bits(eA);
          float eB = aBm*EXP_SCORE(s4B[r]); lrB += eB; pB[r] = bf16bits(eB);
        }
      }
      const int po = (i>>1)*1024 + (i&1)*512;
      *(short4v*)(pwb + po)        = pA;  // set A (queries 0-15)
      *(short4v*)(pwb + po + 2048) = pB;  // set B (queries 16-31)
    }
    // ---- 2 PV chunks (32 keys each); V frags from L2 (coalesced 1KB loads)
    #pragma unroll
    for (int klp=0; klp<2; ++klp){
      const int kc = ph*2 + klp;
      short8 pfA = *(const short8*)(prb + klp*1024);
      short8 pfB = *(const short8*)(prb + klp*1024 + 2048);
      #pragma unroll
      for (int m=0;m<4;m++){
        short8 vf = *(const short8*)(vgf + (kc*4 + m)*1024);
        if (ph<2){ aA0[m] = MFMA_BF16(vf,pfA,aA0[m]); aB0[m] = MFMA_BF16(vf,pfB,aB0[m]); }
        else     { aA1[m] = MFMA_BF16(vf,pfA,aA1[m]); aB1[m] = MFMA_BF16(vf,pfB,aB1[m]); }
      }
    }
  }

  // ---- row-sum reductions (query lives in lane&15; reduce across quads)
  lbA += __shfl_xor(lbA,16); lbA += __shfl_xor(lbA,32);
  lrA += __shfl_xor(lrA,16); lrA += __shfl_xor(lrA,32);
  lbB += __shfl_xor(lbB,16); lbB += __shfl_xor(lbB,32);
  lrB += __shfl_xor(lrB,16); lrB += __shfl_xor(lrB,32);

  const float invbA = 0.5f/lbA;
  const float lregA = ((abA&1u)? lbA : 0.f) + lrA;
  const float invrA = 0.5f/lregA;
  const float cA_A  = invbA + ((abA&1u)? invrA : 0.f);

  const float invbB = 0.5f/lbB;
  const float lregB = ((abB&1u)? lbB : 0.f) + lrB;
  const float invrB = 0.5f/lregB;
  const float cA_B  = invbB + ((abB&1u)? invrB : 0.f);

  // ---- store: lane holds d = m*16 + Q*4 + r for its query (fp32, 16B)
  float* obA = out + (size_t)sA*512 + h*64 + Q*4;
  float* obB = out + (size_t)sB*512 + h*64 + Q*4;
  #pragma unroll
  for (int m=0;m<4;m++){
    f32x4 oA, oB;
    #pragma unroll
    for (int r=0;r<4;r++){
      oA[r] = aA0[m][r]*cA_A + aA1[m][r]*invrA;
      oB[r] = aB0[m][r]*cA_B + aB1[m][r]*invrB;
    }
    *(f32x4*)(obA + m*16) = oA;
    *(f32x4*)(obB + m*16) = oB;
  }
}

extern "C" void kernel_launch(void* const* d_in, const int* in_sizes, int n_in,
                              void* d_out, int out_size, void* d_ws, size_t ws_size,
                              hipStream_t stream) {
  const float* q  = (const float*)d_in[0];
  const float* k  = (const float*)d_in[1];
  const float* v  = (const float*)d_in[2];
  const float* rk = (const float*)d_in[3];
  const float* rv = (const float*)d_in[4];
  const float* rm = (const float*)d_in[5];
  float* out = (float*)d_out;

  char* ws = (char*)d_ws;
  unsigned*       allowed = (unsigned*)ws;                           // 56320*4   = 225280 B
  unsigned short* Kb      = (unsigned short*)(ws + 225280);          // 8*3*128*64*2 = 393216 B
  unsigned short* VT      = (unsigned short*)(ws + 225280 + 393216); // 393216 B

  prep_kernel<<<988, 256, 0, stream>>>(rm, k, v, rk, rv, allowed, Kb, VT);
  dim3 grid(220, 8);
  attn_kernel<<<grid, 512, 0, stream>>>(q, allowed, Kb, VT, out);
}

// Round 8
// 276.751 us; speedup vs baseline: 8.6539x; 8.6539x over previous
//
#include <hip/hip_runtime.h>

typedef short short8  __attribute__((ext_vector_type(8)));
typedef short short4v __attribute__((ext_vector_type(4)));
typedef float f32x4   __attribute__((ext_vector_type(4)));

#define MFMA_BF16(A,B,C) __builtin_amdgcn_mfma_f32_16x16x32_bf16((A),(B),(C),0,0,0)

__device__ __forceinline__ short bf16bits(float f){
  return (short)__builtin_bit_cast(unsigned short, static_cast<__bf16>(f));
}

// exp(s*0.125 - 8) = 2^(s*0.125*log2e - 8*log2e), one v_fma + v_exp
#define EXP_SCORE(s) __builtin_amdgcn_exp2f(__builtin_fmaf((s), 0.18033688011112042f, -11.541560327111707f))

// ---------------- fused preprocessing ----------------
// blocks [0,220): mask preprocessing  (region_masks -> allowed bits)
// blocks [220,988): K/V repack to bf16 in IDENTITY-LANE fragment order:
// each MFMA fragment chunk is 1KB = 64 lanes x 16B with lane l's 16B at
// offset l*16 (conflict-free linear ds_read_b128 / fully-coalesced
// global_load_dwordx4 by construction).
//   K  chunk (t,f):  lane = Qd*16 + ck   holds K[key=t*16+ck][d=f*32+Qd*8+j]
//   V^T chunk (kc,m): lane = Qv*16 + cv  holds V[key=kc*32+Qv*8+jv][d=m*16+cv]
__global__ __launch_bounds__(256) void prep_kernel(const float* __restrict__ rm,
                                                   const float* __restrict__ k,
                                                   const float* __restrict__ v,
                                                   const float* __restrict__ rk,
                                                   const float* __restrict__ rv,
                                                   unsigned* __restrict__ allowed,
                                                   unsigned short* __restrict__ Kb,
                                                   unsigned short* __restrict__ VT){
  const int bid = blockIdx.x;
  if (bid < 220){
    int s = bid*256 + threadIdx.x;
    if (s >= 56320) return;
    int t = s / 3520;
    int rem = s - t*3520;
    int i = rem / 80;
    int j = rem - i*80;
    int y = 2*i, x = 2*j;
    bool bin[2];
    #pragma unroll
    for (int r=0;r<2;r++){
      const float* base = rm + (size_t)r*121*88*160;
      float acc;
      if (t == 0){
        const float* p0 = base + (size_t)(0*88 + y)*160 + x;
        acc = 0.25f*(p0[0]+p0[1]+p0[160]+p0[161]);
      } else {
        const float* pa = base + (size_t)((8*t-4)*88 + y)*160 + x;
        const float* pb = base + (size_t)((8*t-3)*88 + y)*160 + x;
        acc = 0.125f*(pa[0]+pa[1]+pa[160]+pa[161] + pb[0]+pb[1]+pb[160]+pb[161]);
      }
      bin[r] = acc > 0.5f;
    }
    unsigned bits = (bin[0]||bin[1]) ? 0u : 1u;
    if (bin[0]) bits |= 2u;
    if (bin[1]) bits |= 4u;
    allowed[s] = bits;
  } else {
    int idx = (bid-220)*256 + threadIdx.x;   // over 3*128*8*64 = 196608
    if (idx >= 3*128*8*64) return;
    int d   = idx & 63;
    int h   = (idx >> 6) & 7;
    int p   = (idx >> 9) & 127;
    int seg = idx >> 16;
    int low = idx & 65535;                   // (p*8+h)*64+d
    float kv_, vv_;
    if (seg == 0){ kv_ = k[low];                          vv_ = v[low]; }
    else         { kv_ = rk[(size_t)(seg-1)*65536 + low]; vv_ = rv[(size_t)(seg-1)*65536 + low]; }
    const int kk = seg*128 + p;              // key index within head, 0..383
    // K: chunk (t=kk>>4, f=d>>5), lane = ((d>>3)&3)*16 + (kk&15), elem j=d&7
    Kb[(size_t)h*24576 + ((kk>>4)*2 + (d>>5))*512
       + ((((d>>3)&3)*16) + (kk&15))*8 + (d&7)] = (unsigned short)bf16bits(kv_);
    // V^T: chunk (kc=kk>>5, m=d>>4), lane = ((kk>>3)&3)*16 + (d&15), elem jv=kk&7
    VT[(size_t)h*24576 + ((kk>>5)*4 + (d>>4))*512
       + ((((kk>>3)&3)*16) + (d&15))*8 + (kk&7)] = (unsigned short)bf16bits(vv_);
  }
}

// ---------------- fused regional+base attention ----------------
// 512 threads (8 waves) per (head, 128-query chunk); ONE 16-query set per
// wave. Rounds 3-7 showed the dual-set design's 64-float accumulator base
// left no VGPR headroom: full unroll spilled ~37 regs; a runtime phase loop
// demoted the accs to scratch entirely (rule #20, 10GB scratch traffic).
// Single set = 32 acc + 8 qfrag ~ 45 live regs -> full unroll fits 128
// with hoisting headroom -> no spill, real ILP.
// K (48KB) staged in LDS (linear memcpy; fragment permutation in prep);
// V frags read directly from L2 (VT=768KB, L2-resident, coalesced 1KB
// loads). LDS = 48+16 = 64KB -> 2 blocks/CU -> 4 waves/SIMD.
// Phases split into TWO fully-unrolled loops by accumulator target
// (0-1 -> acc0 base, 2-5 -> acc1 regional): compile-time ph everywhere,
// no runtime acc selection.
__global__ __launch_bounds__(512)
void attn_kernel(const float* __restrict__ q,
                 const unsigned* __restrict__ allowed,
                 const unsigned short* __restrict__ Kb,
                 const unsigned short* __restrict__ VT,
                 float* __restrict__ out){
  const int h    = blockIdx.y;
  const int wave = threadIdx.x >> 6;
  const int lane = threadIdx.x & 63;
  const int c    = lane & 15;        // query col / fragment row
  const int Q    = lane >> 4;        // quad

  __shared__ __align__(16) char Ks[49152];   // 24 tiles x 2 frags x 1KB
  __shared__ __align__(16) char Ps[16384];   // 8 waves x 2KB (phase-local)

  const int s = blockIdx.x*128 + wave*16 + c;

  // ---- stage K: issue the 6 loads first; q work overlaps the latency
  const char* kg = (const char*)Kb + (size_t)h*49152;
  short8 st0 = *(const short8*)(kg + wave*6144 + 0*1024 + lane*16);
  short8 st1 = *(const short8*)(kg + wave*6144 + 1*1024 + lane*16);
  short8 st2 = *(const short8*)(kg + wave*6144 + 2*1024 + lane*16);
  short8 st3 = *(const short8*)(kg + wave*6144 + 3*1024 + lane*16);
  short8 st4 = *(const short8*)(kg + wave*6144 + 4*1024 + lane*16);
  short8 st5 = *(const short8*)(kg + wave*6144 + 5*1024 + lane*16);

  // ---- q load -> bf16 frags immediately (8 regs live past here)
  const unsigned ab = allowed[s];
  const float* qp = q + ((size_t)s*8 + h)*64 + Q*8;
  f32x4 q0 = *(const f32x4*)(qp);
  f32x4 q1 = *(const f32x4*)(qp+4);
  f32x4 q2 = *(const f32x4*)(qp+32);
  f32x4 q3 = *(const f32x4*)(qp+36);
  short8 f0, f1;
  #pragma unroll
  for (int j=0;j<4;j++){
    f0[j] = bf16bits(q0[j]); f0[4+j] = bf16bits(q1[j]);
    f1[j] = bf16bits(q2[j]); f1[4+j] = bf16bits(q3[j]);
  }

  // ---- K -> LDS (pure linear, conflict-free)
  *(short8*)(Ks + wave*6144 + 0*1024 + lane*16) = st0;
  *(short8*)(Ks + wave*6144 + 1*1024 + lane*16) = st1;
  *(short8*)(Ks + wave*6144 + 2*1024 + lane*16) = st2;
  *(short8*)(Ks + wave*6144 + 3*1024 + lane*16) = st3;
  *(short8*)(Ks + wave*6144 + 4*1024 + lane*16) = st4;
  *(short8*)(Ks + wave*6144 + 5*1024 + lane*16) = st5;

  __syncthreads();   // staged K visible to all waves

  // ---- identity-lane fragment bases (linear, conflict-free)
  const char* kfb = Ks + lane*16;                                 // + (t*2+f)*1024
  const char* vgf = (const char*)VT + (size_t)h*49152 + lane*16;  // global V frags
  char*       pwb = Ps + wave*2048 + (Q>>1)*256 + c*16 + (Q&1)*8; // + i*512
  const char* prb = Ps + wave*2048 + lane*16;                     // + klp*1024

  const float am1 = (ab>>1)&1u ? 1.f : 0.f;   // region 0 (phases 2-3)
  const float am2 = (ab>>2)&1u ? 1.f : 0.f;   // region 1 (phases 4-5)

  float lb=0.f, lr=0.f;
  f32x4 a0[4], a1[4];
  #pragma unroll
  for (int m=0;m<4;m++){ a0[m]=(f32x4){0,0,0,0}; a1[m]=(f32x4){0,0,0,0}; }

  // ---- base phases (keys 0-127) -> acc0 only
  #pragma unroll
  for (int ph=0; ph<2; ++ph){
    #pragma unroll
    for (int i=0;i<4;i++){
      const int t = ph*4 + i;
      short8 kf0 = *(const short8*)(kfb + (t*2  )*1024);
      short8 kf1 = *(const short8*)(kfb + (t*2+1)*1024);
      f32x4 s4 = {0,0,0,0}; s4 = MFMA_BF16(kf0,f0,s4); s4 = MFMA_BF16(kf1,f1,s4);
      short4v pk;
      #pragma unroll
      for (int r=0;r<4;r++){
        float e = EXP_SCORE(s4[r]); lb += e; pk[r] = bf16bits(e);
      }
      *(short4v*)(pwb + i*512) = pk;
    }
    #pragma unroll
    for (int klp=0; klp<2; ++klp){
      const int kc = ph*2 + klp;
      short8 pf = *(const short8*)(prb + klp*1024);
      #pragma unroll
      for (int m=0;m<4;m++){
        short8 vf = *(const short8*)(vgf + (kc*4 + m)*1024);
        a0[m] = MFMA_BF16(vf, pf, a0[m]);
      }
    }
  }

  // ---- regional phases (keys 128-383) -> acc1 only
  #pragma unroll
  for (int ph=2; ph<6; ++ph){
    const float am = (ph<4) ? am1 : am2;      // compile-time select (unrolled)
    #pragma unroll
    for (int i=0;i<4;i++){
      const int t = ph*4 + i;
      short8 kf0 = *(const short8*)(kfb + (t*2  )*1024);
      short8 kf1 = *(const short8*)(kfb + (t*2+1)*1024);
      f32x4 s4 = {0,0,0,0}; s4 = MFMA_BF16(kf0,f0,s4); s4 = MFMA_BF16(kf1,f1,s4);
      short4v pk;
      #pragma unroll
      for (int r=0;r<4;r++){
        float e = am*EXP_SCORE(s4[r]); lr += e; pk[r] = bf16bits(e);
      }
      *(short4v*)(pwb + i*512) = pk;
    }
    #pragma unroll
    for (int klp=0; klp<2; ++klp){
      const int kc = ph*2 + klp;
      short8 pf = *(const short8*)(prb + klp*1024);
      #pragma unroll
      for (int m=0;m<4;m++){
        short8 vf = *(const short8*)(vgf + (kc*4 + m)*1024);
        a1[m] = MFMA_BF16(vf, pf, a1[m]);
      }
    }
  }

  // ---- row-sum reductions (query lives in lane&15; reduce across quads)
  lb += __shfl_xor(lb,16); lb += __shfl_xor(lb,32);
  lr += __shfl_xor(lr,16); lr += __shfl_xor(lr,32);

  const float invb = 0.5f/lb;
  const float lreg = ((ab&1u)? lb : 0.f) + lr;
  const float invr = 0.5f/lreg;
  const float cA   = invb + ((ab&1u)? invr : 0.f);

  // ---- store: lane holds d = m*16 + Q*4 + r for query s (fp32, 16B)
  float* ob = out + (size_t)s*512 + h*64 + Q*4;
  #pragma unroll
  for (int m=0;m<4;m++){
    f32x4 o;
    #pragma unroll
    for (int r=0;r<4;r++) o[r] = a0[m][r]*cA + a1[m][r]*invr;
    *(f32x4*)(ob + m*16) = o;
  }
}

extern "C" void kernel_launch(void* const* d_in, const int* in_sizes, int n_in,
                              void* d_out, int out_size, void* d_ws, size_t ws_size,
                              hipStream_t stream) {
  const float* q  = (const float*)d_in[0];
  const float* k  = (const float*)d_in[1];
  const float* v  = (const float*)d_in[2];
  const float* rk = (const float*)d_in[3];
  const float* rv = (const float*)d_in[4];
  const float* rm = (const float*)d_in[5];
  float* out = (float*)d_out;

  char* ws = (char*)d_ws;
  unsigned*       allowed = (unsigned*)ws;                           // 56320*4   = 225280 B
  unsigned short* Kb      = (unsigned short*)(ws + 225280);          // 8*3*128*64*2 = 393216 B
  unsigned short* VT      = (unsigned short*)(ws + 225280 + 393216); // 393216 B

  prep_kernel<<<988, 256, 0, stream>>>(rm, k, v, rk, rv, allowed, Kb, VT);
  dim3 grid(440, 8);
  attn_kernel<<<grid, 512, 0, stream>>>(q, allowed, Kb, VT, out);
}

// Round 9
// 271.219 us; speedup vs baseline: 8.8304x; 1.0204x over previous
//
#include <hip/hip_runtime.h>

typedef short short8  __attribute__((ext_vector_type(8)));
typedef short short4v __attribute__((ext_vector_type(4)));
typedef float f32x4   __attribute__((ext_vector_type(4)));

#define MFMA_BF16(A,B,C) __builtin_amdgcn_mfma_f32_16x16x32_bf16((A),(B),(C),0,0,0)

__device__ __forceinline__ short bf16bits(float f){
  return (short)__builtin_bit_cast(unsigned short, static_cast<__bf16>(f));
}

// exp(s*0.125 - 8) = 2^(s*0.125*log2e - 8*log2e), one v_fma + v_exp
#define EXP_SCORE(s) __builtin_amdgcn_exp2f(__builtin_fmaf((s), 0.18033688011112042f, -11.541560327111707f))

// ---------------- fused preprocessing ----------------
// blocks [0,220): mask preprocessing  (region_masks -> allowed bits)
// blocks [220,988): K/V repack to bf16 in IDENTITY-LANE fragment order:
// each MFMA fragment chunk is 1KB = 64 lanes x 16B with lane l's 16B at
// offset l*16 (conflict-free linear ds_read_b128 / fully-coalesced
// global_load_dwordx4 by construction).
//   K  chunk (t,f):  lane = Qd*16 + ck   holds K[key=t*16+ck][d=f*32+Qd*8+j]
//   V^T chunk (kc,m): lane = Qv*16 + cv  holds V[key=kc*32+Qv*8+jv][d=m*16+cv]
__global__ __launch_bounds__(256) void prep_kernel(const float* __restrict__ rm,
                                                   const float* __restrict__ k,
                                                   const float* __restrict__ v,
                                                   const float* __restrict__ rk,
                                                   const float* __restrict__ rv,
                                                   unsigned* __restrict__ allowed,
                                                   unsigned short* __restrict__ Kb,
                                                   unsigned short* __restrict__ VT){
  const int bid = blockIdx.x;
  if (bid < 220){
    int s = bid*256 + threadIdx.x;
    if (s >= 56320) return;
    int t = s / 3520;
    int rem = s - t*3520;
    int i = rem / 80;
    int j = rem - i*80;
    int y = 2*i, x = 2*j;
    bool bin[2];
    #pragma unroll
    for (int r=0;r<2;r++){
      const float* base = rm + (size_t)r*121*88*160;
      float acc;
      if (t == 0){
        const float* p0 = base + (size_t)(0*88 + y)*160 + x;
        acc = 0.25f*(p0[0]+p0[1]+p0[160]+p0[161]);
      } else {
        const float* pa = base + (size_t)((8*t-4)*88 + y)*160 + x;
        const float* pb = base + (size_t)((8*t-3)*88 + y)*160 + x;
        acc = 0.125f*(pa[0]+pa[1]+pa[160]+pa[161] + pb[0]+pb[1]+pb[160]+pb[161]);
      }
      bin[r] = acc > 0.5f;
    }
    unsigned bits = (bin[0]||bin[1]) ? 0u : 1u;
    if (bin[0]) bits |= 2u;
    if (bin[1]) bits |= 4u;
    allowed[s] = bits;
  } else {
    int idx = (bid-220)*256 + threadIdx.x;   // over 3*128*8*64 = 196608
    if (idx >= 3*128*8*64) return;
    int d   = idx & 63;
    int h   = (idx >> 6) & 7;
    int p   = (idx >> 9) & 127;
    int seg = idx >> 16;
    int low = idx & 65535;                   // (p*8+h)*64+d
    float kv_, vv_;
    if (seg == 0){ kv_ = k[low];                          vv_ = v[low]; }
    else         { kv_ = rk[(size_t)(seg-1)*65536 + low]; vv_ = rv[(size_t)(seg-1)*65536 + low]; }
    const int kk = seg*128 + p;              // key index within head, 0..383
    // K: chunk (t=kk>>4, f=d>>5), lane = ((d>>3)&3)*16 + (kk&15), elem j=d&7
    Kb[(size_t)h*24576 + ((kk>>4)*2 + (d>>5))*512
       + ((((d>>3)&3)*16) + (kk&15))*8 + (d&7)] = (unsigned short)bf16bits(kv_);
    // V^T: chunk (kc=kk>>5, m=d>>4), lane = ((kk>>3)&3)*16 + (d&15), elem jv=kk&7
    VT[(size_t)h*24576 + ((kk>>5)*4 + (d>>4))*512
       + ((((kk>>3)&3)*16) + (d&15))*8 + (kk&7)] = (unsigned short)bf16bits(vv_);
  }
}

// ---------------- fused regional+base attention ----------------
// 512 threads (8 waves) per (head, 128-query chunk); one 16-query set per
// wave (round 8's no-spill structure: 32 acc + 8 qfrag base, full unroll,
// compile-time acc selection everywhere).
// K (48KB) staged in LDS; V frags read from L2 (VT=768KB, L2-resident,
// coalesced 1KB loads). LDS = 48+16 = 64KB -> 2 blocks/CU -> 4 waves/SIMD.
// ROUND 9: manual single-buffer V register prefetch. Round 8's VGPR=68
// showed the compiler scheduled V loads at their uses (minimal regs, no
// prefetch distance) -> ~300-500cy L2 latency exposed per phase. Named
// v0..v7 hold the phase's 8 V fragments; loads issue one phase ahead
// (phase 0 pre-barrier, phase p+1 right after phase p's PV consumes the
// buffer) so latency hides under the next score section. All indices
// compile-time; single buffer = no aliasing.
__global__ __launch_bounds__(512)
void attn_kernel(const float* __restrict__ q,
                 const unsigned* __restrict__ allowed,
                 const unsigned short* __restrict__ Kb,
                 const unsigned short* __restrict__ VT,
                 float* __restrict__ out){
  const int h    = blockIdx.y;
  const int wave = threadIdx.x >> 6;
  const int lane = threadIdx.x & 63;
  const int c    = lane & 15;        // query col / fragment row
  const int Q    = lane >> 4;        // quad

  __shared__ __align__(16) char Ks[49152];   // 24 tiles x 2 frags x 1KB
  __shared__ __align__(16) char Ps[16384];   // 8 waves x 2KB (phase-local)

  const int s = blockIdx.x*128 + wave*16 + c;

  // ---- stage K: issue the 6 loads first; q work overlaps the latency
  const char* kg = (const char*)Kb + (size_t)h*49152;
  short8 st0 = *(const short8*)(kg + wave*6144 + 0*1024 + lane*16);
  short8 st1 = *(const short8*)(kg + wave*6144 + 1*1024 + lane*16);
  short8 st2 = *(const short8*)(kg + wave*6144 + 2*1024 + lane*16);
  short8 st3 = *(const short8*)(kg + wave*6144 + 3*1024 + lane*16);
  short8 st4 = *(const short8*)(kg + wave*6144 + 4*1024 + lane*16);
  short8 st5 = *(const short8*)(kg + wave*6144 + 5*1024 + lane*16);

  // ---- q load -> bf16 frags immediately (8 regs live past here)
  const unsigned ab = allowed[s];
  const float* qp = q + ((size_t)s*8 + h)*64 + Q*8;
  f32x4 q0 = *(const f32x4*)(qp);
  f32x4 q1 = *(const f32x4*)(qp+4);
  f32x4 q2 = *(const f32x4*)(qp+32);
  f32x4 q3 = *(const f32x4*)(qp+36);
  short8 f0, f1;
  #pragma unroll
  for (int j=0;j<4;j++){
    f0[j] = bf16bits(q0[j]); f0[4+j] = bf16bits(q1[j]);
    f1[j] = bf16bits(q2[j]); f1[4+j] = bf16bits(q3[j]);
  }

  // ---- K -> LDS (pure linear, conflict-free)
  *(short8*)(Ks + wave*6144 + 0*1024 + lane*16) = st0;
  *(short8*)(Ks + wave*6144 + 1*1024 + lane*16) = st1;
  *(short8*)(Ks + wave*6144 + 2*1024 + lane*16) = st2;
  *(short8*)(Ks + wave*6144 + 3*1024 + lane*16) = st3;
  *(short8*)(Ks + wave*6144 + 4*1024 + lane*16) = st4;
  *(short8*)(Ks + wave*6144 + 5*1024 + lane*16) = st5;

  // ---- identity-lane fragment bases (linear, conflict-free)
  const char* kfb = Ks + lane*16;                                 // + (t*2+f)*1024
  const char* vgf = (const char*)VT + (size_t)h*49152 + lane*16;  // global V frags
  char*       pwb = Ps + wave*2048 + (Q>>1)*256 + c*16 + (Q&1)*8; // + i*512
  const char* prb = Ps + wave*2048 + lane*16;                     // + klp*1024

  // ---- V prefetch buffer (single, compile-time indexed)
  short8 v0, v1, v2, v3, v4, v5, v6, v7;
#define VLOAD(ph)                                                     \
  v0 = *(const short8*)(vgf + (((ph)*2+0)*4+0)*1024);                 \
  v1 = *(const short8*)(vgf + (((ph)*2+0)*4+1)*1024);                 \
  v2 = *(const short8*)(vgf + (((ph)*2+0)*4+2)*1024);                 \
  v3 = *(const short8*)(vgf + (((ph)*2+0)*4+3)*1024);                 \
  v4 = *(const short8*)(vgf + (((ph)*2+1)*4+0)*1024);                 \
  v5 = *(const short8*)(vgf + (((ph)*2+1)*4+1)*1024);                 \
  v6 = *(const short8*)(vgf + (((ph)*2+1)*4+2)*1024);                 \
  v7 = *(const short8*)(vgf + (((ph)*2+1)*4+3)*1024);

#define DO_SCORES(ph, LSUM, AM)                                       \
  {                                                                   \
    _Pragma("unroll")                                                 \
    for (int i=0;i<4;i++){                                            \
      const int t = (ph)*4 + i;                                       \
      short8 kf0 = *(const short8*)(kfb + (t*2  )*1024);              \
      short8 kf1 = *(const short8*)(kfb + (t*2+1)*1024);              \
      f32x4 s4 = {0,0,0,0};                                           \
      s4 = MFMA_BF16(kf0,f0,s4); s4 = MFMA_BF16(kf1,f1,s4);           \
      short4v pk;                                                     \
      _Pragma("unroll")                                               \
      for (int r=0;r<4;r++){                                          \
        float e = (AM)*EXP_SCORE(s4[r]); LSUM += e;                   \
        pk[r] = bf16bits(e);                                          \
      }                                                               \
      *(short4v*)(pwb + i*512) = pk;                                  \
    }                                                                 \
  }

#define DO_PV(ACC)                                                    \
  {                                                                   \
    short8 pf0 = *(const short8*)(prb);                               \
    short8 pf1 = *(const short8*)(prb + 1024);                        \
    ACC[0] = MFMA_BF16(v0, pf0, ACC[0]);                              \
    ACC[1] = MFMA_BF16(v1, pf0, ACC[1]);                              \
    ACC[2] = MFMA_BF16(v2, pf0, ACC[2]);                              \
    ACC[3] = MFMA_BF16(v3, pf0, ACC[3]);                              \
    ACC[0] = MFMA_BF16(v4, pf1, ACC[0]);                              \
    ACC[1] = MFMA_BF16(v5, pf1, ACC[1]);                              \
    ACC[2] = MFMA_BF16(v6, pf1, ACC[2]);                              \
    ACC[3] = MFMA_BF16(v7, pf1, ACC[3]);                              \
  }

  // phase-0 V loads before the barrier: the barrier's vmcnt drain
  // completes them alongside K staging, free
  VLOAD(0);

  __syncthreads();   // staged K visible to all waves

  const float am1 = (ab>>1)&1u ? 1.f : 0.f;   // region 0 (phases 2-3)
  const float am2 = (ab>>2)&1u ? 1.f : 0.f;   // region 1 (phases 4-5)

  float lb=0.f, lr=0.f;
  f32x4 a0[4], a1[4];
  #pragma unroll
  for (int m=0;m<4;m++){ a0[m]=(f32x4){0,0,0,0}; a1[m]=(f32x4){0,0,0,0}; }

  // ---- 6 phases, fully unrolled, V loads one phase ahead of use
  DO_SCORES(0, lb, 1.0f);  DO_PV(a0);  VLOAD(1);
  DO_SCORES(1, lb, 1.0f);  DO_PV(a0);  VLOAD(2);
  DO_SCORES(2, lr, am1);   DO_PV(a1);  VLOAD(3);
  DO_SCORES(3, lr, am1);   DO_PV(a1);  VLOAD(4);
  DO_SCORES(4, lr, am2);   DO_PV(a1);  VLOAD(5);
  DO_SCORES(5, lr, am2);   DO_PV(a1);

  // ---- row-sum reductions (query lives in lane&15; reduce across quads)
  lb += __shfl_xor(lb,16); lb += __shfl_xor(lb,32);
  lr += __shfl_xor(lr,16); lr += __shfl_xor(lr,32);

  const float invb = 0.5f/lb;
  const float lreg = ((ab&1u)? lb : 0.f) + lr;
  const float invr = 0.5f/lreg;
  const float cA   = invb + ((ab&1u)? invr : 0.f);

  // ---- store: lane holds d = m*16 + Q*4 + r for query s (fp32, 16B)
  float* ob = out + (size_t)s*512 + h*64 + Q*4;
  #pragma unroll
  for (int m=0;m<4;m++){
    f32x4 o;
    #pragma unroll
    for (int r=0;r<4;r++) o[r] = a0[m][r]*cA + a1[m][r]*invr;
    *(f32x4*)(ob + m*16) = o;
  }
}

extern "C" void kernel_launch(void* const* d_in, const int* in_sizes, int n_in,
                              void* d_out, int out_size, void* d_ws, size_t ws_size,
                              hipStream_t stream) {
  const float* q  = (const float*)d_in[0];
  const float* k  = (const float*)d_in[1];
  const float* v  = (const float*)d_in[2];
  const float* rk = (const float*)d_in[3];
  const float* rv = (const float*)d_in[4];
  const float* rm = (const float*)d_in[5];
  float* out = (float*)d_out;

  char* ws = (char*)d_ws;
  unsigned*       allowed = (unsigned*)ws;                           // 56320*4   = 225280 B
  unsigned short* Kb      = (unsigned short*)(ws + 225280);          // 8*3*128*64*2 = 393216 B
  unsigned short* VT      = (unsigned short*)(ws + 225280 + 393216); // 393216 B

  prep_kernel<<<988, 256, 0, stream>>>(rm, k, v, rk, rv, allowed, Kb, VT);
  dim3 grid(440, 8);
  attn_kernel<<<grid, 512, 0, stream>>>(q, allowed, Kb, VT, out);
}

// Round 10
// 266.313 us; speedup vs baseline: 8.9931x; 1.0184x over previous
//
#include <hip/hip_runtime.h>

typedef short short8  __attribute__((ext_vector_type(8)));
typedef short short4v __attribute__((ext_vector_type(4)));
typedef float f32x4   __attribute__((ext_vector_type(4)));

#define MFMA_BF16(A,B,C) __builtin_amdgcn_mfma_f32_16x16x32_bf16((A),(B),(C),0,0,0)

__device__ __forceinline__ short bf16bits(float f){
  return (short)__builtin_bit_cast(unsigned short, static_cast<__bf16>(f));
}

// exp(s*0.125 - 8) = 2^(s*0.125*log2e - 8*log2e), one v_fma + v_exp
#define EXP_SCORE(s) __builtin_amdgcn_exp2f(__builtin_fmaf((s), 0.18033688011112042f, -11.541560327111707f))

// ---------------- fused preprocessing ----------------
// blocks [0,220): mask preprocessing  (region_masks -> allowed bits)
// blocks [220,988): K/V repack to bf16 in IDENTITY-LANE fragment order:
// each MFMA fragment chunk is 1KB = 64 lanes x 16B with lane l's 16B at
// offset l*16 (conflict-free linear ds_read_b128 / fully-coalesced
// global_load_dwordx4 by construction).
//   K  chunk (t,f):  lane = Qd*16 + ck   holds K[key=t*16+ck][d=f*32+Qd*8+j]
//   V^T chunk (kc,m): lane = Qv*16 + cv  holds V[key=kc*32+Qv*8+jv][d=m*16+cv]
__global__ __launch_bounds__(256) void prep_kernel(const float* __restrict__ rm,
                                                   const float* __restrict__ k,
                                                   const float* __restrict__ v,
                                                   const float* __restrict__ rk,
                                                   const float* __restrict__ rv,
                                                   unsigned* __restrict__ allowed,
                                                   unsigned short* __restrict__ Kb,
                                                   unsigned short* __restrict__ VT){
  const int bid = blockIdx.x;
  if (bid < 220){
    int s = bid*256 + threadIdx.x;
    if (s >= 56320) return;
    int t = s / 3520;
    int rem = s - t*3520;
    int i = rem / 80;
    int j = rem - i*80;
    int y = 2*i, x = 2*j;
    bool bin[2];
    #pragma unroll
    for (int r=0;r<2;r++){
      const float* base = rm + (size_t)r*121*88*160;
      float acc;
      if (t == 0){
        const float* p0 = base + (size_t)(0*88 + y)*160 + x;
        acc = 0.25f*(p0[0]+p0[1]+p0[160]+p0[161]);
      } else {
        const float* pa = base + (size_t)((8*t-4)*88 + y)*160 + x;
        const float* pb = base + (size_t)((8*t-3)*88 + y)*160 + x;
        acc = 0.125f*(pa[0]+pa[1]+pa[160]+pa[161] + pb[0]+pb[1]+pb[160]+pb[161]);
      }
      bin[r] = acc > 0.5f;
    }
    unsigned bits = (bin[0]||bin[1]) ? 0u : 1u;
    if (bin[0]) bits |= 2u;
    if (bin[1]) bits |= 4u;
    allowed[s] = bits;
  } else {
    int idx = (bid-220)*256 + threadIdx.x;   // over 3*128*8*64 = 196608
    if (idx >= 3*128*8*64) return;
    int d   = idx & 63;
    int h   = (idx >> 6) & 7;
    int p   = (idx >> 9) & 127;
    int seg = idx >> 16;
    int low = idx & 65535;                   // (p*8+h)*64+d
    float kv_, vv_;
    if (seg == 0){ kv_ = k[low];                          vv_ = v[low]; }
    else         { kv_ = rk[(size_t)(seg-1)*65536 + low]; vv_ = rv[(size_t)(seg-1)*65536 + low]; }
    const int kk = seg*128 + p;              // key index within head, 0..383
    // K: chunk (t=kk>>4, f=d>>5), lane = ((d>>3)&3)*16 + (kk&15), elem j=d&7
    Kb[(size_t)h*24576 + ((kk>>4)*2 + (d>>5))*512
       + ((((d>>3)&3)*16) + (kk&15))*8 + (d&7)] = (unsigned short)bf16bits(kv_);
    // V^T: chunk (kc=kk>>5, m=d>>4), lane = ((kk>>3)&3)*16 + (d&15), elem jv=kk&7
    VT[(size_t)h*24576 + ((kk>>5)*4 + (d>>4))*512
       + ((((kk>>3)&3)*16) + (d&15))*8 + (kk&7)] = (unsigned short)bf16bits(vv_);
  }
}

// ---------------- fused regional+base attention ----------------
// 512 threads (8 waves) per (head, 128-query chunk); one 16-query set per
// wave (round 8's no-spill structure: 32 acc + 8 qfrag base, full unroll,
// compile-time acc selection everywhere).
// K (48KB) staged in LDS; V frags read from L2 (VT=768KB, L2-resident,
// coalesced 1KB loads). LDS = 48+16 = 64KB -> 2 blocks/CU -> 4 waves/SIMD.
// ROUND 10: round 9's source-level V prefetch was silently sunk back to the
// uses by the scheduler (VGPR stayed 68, dur unchanged). Pin the issue point
// with __builtin_amdgcn_sched_barrier(0) right after each VLOAD (rule #18:
// the scheduler moves code across source placement; sched_barrier(0) is the
// fence). The 8 global_load_dwordx4 then issue BEFORE the next score
// section (~400+ cy of ds_read/MFMA/exp) and drain under it via counted
// vmcnt, instead of stalling PV. Cost: 32 VGPRs in flight (68+32 ~ 100,
// under the 128 budget; LDS remains the occupancy limiter).
__global__ __launch_bounds__(512)
void attn_kernel(const float* __restrict__ q,
                 const unsigned* __restrict__ allowed,
                 const unsigned short* __restrict__ Kb,
                 const unsigned short* __restrict__ VT,
                 float* __restrict__ out){
  const int h    = blockIdx.y;
  const int wave = threadIdx.x >> 6;
  const int lane = threadIdx.x & 63;
  const int c    = lane & 15;        // query col / fragment row
  const int Q    = lane >> 4;        // quad

  __shared__ __align__(16) char Ks[49152];   // 24 tiles x 2 frags x 1KB
  __shared__ __align__(16) char Ps[16384];   // 8 waves x 2KB (phase-local)

  const int s = blockIdx.x*128 + wave*16 + c;

  // ---- stage K: issue the 6 loads first; q work overlaps the latency
  const char* kg = (const char*)Kb + (size_t)h*49152;
  short8 st0 = *(const short8*)(kg + wave*6144 + 0*1024 + lane*16);
  short8 st1 = *(const short8*)(kg + wave*6144 + 1*1024 + lane*16);
  short8 st2 = *(const short8*)(kg + wave*6144 + 2*1024 + lane*16);
  short8 st3 = *(const short8*)(kg + wave*6144 + 3*1024 + lane*16);
  short8 st4 = *(const short8*)(kg + wave*6144 + 4*1024 + lane*16);
  short8 st5 = *(const short8*)(kg + wave*6144 + 5*1024 + lane*16);

  // ---- q load -> bf16 frags immediately (8 regs live past here)
  const unsigned ab = allowed[s];
  const float* qp = q + ((size_t)s*8 + h)*64 + Q*8;
  f32x4 q0 = *(const f32x4*)(qp);
  f32x4 q1 = *(const f32x4*)(qp+4);
  f32x4 q2 = *(const f32x4*)(qp+32);
  f32x4 q3 = *(const f32x4*)(qp+36);
  short8 f0, f1;
  #pragma unroll
  for (int j=0;j<4;j++){
    f0[j] = bf16bits(q0[j]); f0[4+j] = bf16bits(q1[j]);
    f1[j] = bf16bits(q2[j]); f1[4+j] = bf16bits(q3[j]);
  }

  // ---- K -> LDS (pure linear, conflict-free)
  *(short8*)(Ks + wave*6144 + 0*1024 + lane*16) = st0;
  *(short8*)(Ks + wave*6144 + 1*1024 + lane*16) = st1;
  *(short8*)(Ks + wave*6144 + 2*1024 + lane*16) = st2;
  *(short8*)(Ks + wave*6144 + 3*1024 + lane*16) = st3;
  *(short8*)(Ks + wave*6144 + 4*1024 + lane*16) = st4;
  *(short8*)(Ks + wave*6144 + 5*1024 + lane*16) = st5;

  // ---- identity-lane fragment bases (linear, conflict-free)
  const char* kfb = Ks + lane*16;                                 // + (t*2+f)*1024
  const char* vgf = (const char*)VT + (size_t)h*49152 + lane*16;  // global V frags
  char*       pwb = Ps + wave*2048 + (Q>>1)*256 + c*16 + (Q&1)*8; // + i*512
  const char* prb = Ps + wave*2048 + lane*16;                     // + klp*1024

  // ---- V prefetch buffer (single, compile-time indexed)
  short8 v0, v1, v2, v3, v4, v5, v6, v7;
#define VLOAD(ph)                                                     \
  v0 = *(const short8*)(vgf + (((ph)*2+0)*4+0)*1024);                 \
  v1 = *(const short8*)(vgf + (((ph)*2+0)*4+1)*1024);                 \
  v2 = *(const short8*)(vgf + (((ph)*2+0)*4+2)*1024);                 \
  v3 = *(const short8*)(vgf + (((ph)*2+0)*4+3)*1024);                 \
  v4 = *(const short8*)(vgf + (((ph)*2+1)*4+0)*1024);                 \
  v5 = *(const short8*)(vgf + (((ph)*2+1)*4+1)*1024);                 \
  v6 = *(const short8*)(vgf + (((ph)*2+1)*4+2)*1024);                 \
  v7 = *(const short8*)(vgf + (((ph)*2+1)*4+3)*1024);                 \
  __builtin_amdgcn_sched_barrier(0);   /* pin: loads may not sink */

#define DO_SCORES(ph, LSUM, AM)                                       \
  {                                                                   \
    _Pragma("unroll")                                                 \
    for (int i=0;i<4;i++){                                            \
      const int t = (ph)*4 + i;                                       \
      short8 kf0 = *(const short8*)(kfb + (t*2  )*1024);              \
      short8 kf1 = *(const short8*)(kfb + (t*2+1)*1024);              \
      f32x4 s4 = {0,0,0,0};                                           \
      s4 = MFMA_BF16(kf0,f0,s4); s4 = MFMA_BF16(kf1,f1,s4);           \
      short4v pk;                                                     \
      _Pragma("unroll")                                               \
      for (int r=0;r<4;r++){                                          \
        float e = (AM)*EXP_SCORE(s4[r]); LSUM += e;                   \
        pk[r] = bf16bits(e);                                          \
      }                                                               \
      *(short4v*)(pwb + i*512) = pk;                                  \
    }                                                                 \
  }

#define DO_PV(ACC)                                                    \
  {                                                                   \
    short8 pf0 = *(const short8*)(prb);                               \
    short8 pf1 = *(const short8*)(prb + 1024);                        \
    ACC[0] = MFMA_BF16(v0, pf0, ACC[0]);                              \
    ACC[1] = MFMA_BF16(v1, pf0, ACC[1]);                              \
    ACC[2] = MFMA_BF16(v2, pf0, ACC[2]);                              \
    ACC[3] = MFMA_BF16(v3, pf0, ACC[3]);                              \
    ACC[0] = MFMA_BF16(v4, pf1, ACC[0]);                              \
    ACC[1] = MFMA_BF16(v5, pf1, ACC[1]);                              \
    ACC[2] = MFMA_BF16(v6, pf1, ACC[2]);                              \
    ACC[3] = MFMA_BF16(v7, pf1, ACC[3]);                              \
  }

  // phase-0 V loads before the barrier: the barrier's vmcnt drain
  // completes them alongside K staging, free
  VLOAD(0);

  __syncthreads();   // staged K visible to all waves

  const float am1 = (ab>>1)&1u ? 1.f : 0.f;   // region 0 (phases 2-3)
  const float am2 = (ab>>2)&1u ? 1.f : 0.f;   // region 1 (phases 4-5)

  float lb=0.f, lr=0.f;
  f32x4 a0[4], a1[4];
  #pragma unroll
  for (int m=0;m<4;m++){ a0[m]=(f32x4){0,0,0,0}; a1[m]=(f32x4){0,0,0,0}; }

  // ---- 6 phases, fully unrolled; V loads pinned one phase ahead of use
  DO_SCORES(0, lb, 1.0f);  DO_PV(a0);  VLOAD(1);
  DO_SCORES(1, lb, 1.0f);  DO_PV(a0);  VLOAD(2);
  DO_SCORES(2, lr, am1);   DO_PV(a1);  VLOAD(3);
  DO_SCORES(3, lr, am1);   DO_PV(a1);  VLOAD(4);
  DO_SCORES(4, lr, am2);   DO_PV(a1);  VLOAD(5);
  DO_SCORES(5, lr, am2);   DO_PV(a1);

  // ---- row-sum reductions (query lives in lane&15; reduce across quads)
  lb += __shfl_xor(lb,16); lb += __shfl_xor(lb,32);
  lr += __shfl_xor(lr,16); lr += __shfl_xor(lr,32);

  const float invb = 0.5f/lb;
  const float lreg = ((ab&1u)? lb : 0.f) + lr;
  const float invr = 0.5f/lreg;
  const float cA   = invb + ((ab&1u)? invr : 0.f);

  // ---- store: lane holds d = m*16 + Q*4 + r for query s (fp32, 16B)
  float* ob = out + (size_t)s*512 + h*64 + Q*4;
  #pragma unroll
  for (int m=0;m<4;m++){
    f32x4 o;
    #pragma unroll
    for (int r=0;r<4;r++) o[r] = a0[m][r]*cA + a1[m][r]*invr;
    *(f32x4*)(ob + m*16) = o;
  }
}

extern "C" void kernel_launch(void* const* d_in, const int* in_sizes, int n_in,
                              void* d_out, int out_size, void* d_ws, size_t ws_size,
                              hipStream_t stream) {
  const float* q  = (const float*)d_in[0];
  const float* k  = (const float*)d_in[1];
  const float* v  = (const float*)d_in[2];
  const float* rk = (const float*)d_in[3];
  const float* rv = (const float*)d_in[4];
  const float* rm = (const float*)d_in[5];
  float* out = (float*)d_out;

  char* ws = (char*)d_ws;
  unsigned*       allowed = (unsigned*)ws;                           // 56320*4   = 225280 B
  unsigned short* Kb      = (unsigned short*)(ws + 225280);          // 8*3*128*64*2 = 393216 B
  unsigned short* VT      = (unsigned short*)(ws + 225280 + 393216); // 393216 B

  prep_kernel<<<988, 256, 0, stream>>>(rm, k, v, rk, rv, allowed, Kb, VT);
  dim3 grid(440, 8);
  attn_kernel<<<grid, 512, 0, stream>>>(q, allowed, Kb, VT, out);
}

// Round 11
// 264.123 us; speedup vs baseline: 9.0677x; 1.0083x over previous
//
#include <hip/hip_runtime.h>

typedef short short8  __attribute__((ext_vector_type(8)));
typedef short short4v __attribute__((ext_vector_type(4)));
typedef float f32x4   __attribute__((ext_vector_type(4)));

#define MFMA_BF16(A,B,C) __builtin_amdgcn_mfma_f32_16x16x32_bf16((A),(B),(C),0,0,0)

__device__ __forceinline__ short bf16bits(float f){
  return (short)__builtin_bit_cast(unsigned short, static_cast<__bf16>(f));
}

// exp(s*0.125 - 8) = 2^(s*0.125*log2e - 8*log2e), one v_fma + v_exp
#define EXP_SCORE(s) __builtin_amdgcn_exp2f(__builtin_fmaf((s), 0.18033688011112042f, -11.541560327111707f))

// ---------------- fused preprocessing ----------------
// blocks [0,220): mask preprocessing  (region_masks -> allowed bits)
// blocks [220,988): K/V repack to bf16 in IDENTITY-LANE fragment order:
// each MFMA fragment chunk is 1KB = 64 lanes x 16B with lane l's 16B at
// offset l*16 (conflict-free linear ds_read_b128 / fully-coalesced
// global_load_dwordx4 by construction).
//   K  chunk (t,f):  lane = Qd*16 + ck   holds K[key=t*16+ck][d=f*32+Qd*8+j]
//   V^T chunk (kc,m): lane = Qv*16 + cv  holds V[key=kc*32+Qv*8+jv][d=m*16+cv]
__global__ __launch_bounds__(256) void prep_kernel(const float* __restrict__ rm,
                                                   const float* __restrict__ k,
                                                   const float* __restrict__ v,
                                                   const float* __restrict__ rk,
                                                   const float* __restrict__ rv,
                                                   unsigned* __restrict__ allowed,
                                                   unsigned short* __restrict__ Kb,
                                                   unsigned short* __restrict__ VT){
  const int bid = blockIdx.x;
  if (bid < 220){
    int s = bid*256 + threadIdx.x;
    if (s >= 56320) return;
    int t = s / 3520;
    int rem = s - t*3520;
    int i = rem / 80;
    int j = rem - i*80;
    int y = 2*i, x = 2*j;
    bool bin[2];
    #pragma unroll
    for (int r=0;r<2;r++){
      const float* base = rm + (size_t)r*121*88*160;
      float acc;
      if (t == 0){
        const float* p0 = base + (size_t)(0*88 + y)*160 + x;
        acc = 0.25f*(p0[0]+p0[1]+p0[160]+p0[161]);
      } else {
        const float* pa = base + (size_t)((8*t-4)*88 + y)*160 + x;
        const float* pb = base + (size_t)((8*t-3)*88 + y)*160 + x;
        acc = 0.125f*(pa[0]+pa[1]+pa[160]+pa[161] + pb[0]+pb[1]+pb[160]+pb[161]);
      }
      bin[r] = acc > 0.5f;
    }
    unsigned bits = (bin[0]||bin[1]) ? 0u : 1u;
    if (bin[0]) bits |= 2u;
    if (bin[1]) bits |= 4u;
    allowed[s] = bits;
  } else {
    int idx = (bid-220)*256 + threadIdx.x;   // over 3*128*8*64 = 196608
    if (idx >= 3*128*8*64) return;
    int d   = idx & 63;
    int h   = (idx >> 6) & 7;
    int p   = (idx >> 9) & 127;
    int seg = idx >> 16;
    int low = idx & 65535;                   // (p*8+h)*64+d
    float kv_, vv_;
    if (seg == 0){ kv_ = k[low];                          vv_ = v[low]; }
    else         { kv_ = rk[(size_t)(seg-1)*65536 + low]; vv_ = rv[(size_t)(seg-1)*65536 + low]; }
    const int kk = seg*128 + p;              // key index within head, 0..383
    // K: chunk (t=kk>>4, f=d>>5), lane = ((d>>3)&3)*16 + (kk&15), elem j=d&7
    Kb[(size_t)h*24576 + ((kk>>4)*2 + (d>>5))*512
       + ((((d>>3)&3)*16) + (kk&15))*8 + (d&7)] = (unsigned short)bf16bits(kv_);
    // V^T: chunk (kc=kk>>5, m=d>>4), lane = ((kk>>3)&3)*16 + (d&15), elem jv=kk&7
    VT[(size_t)h*24576 + ((kk>>5)*4 + (d>>4))*512
       + ((((kk>>3)&3)*16) + (d&15))*8 + (kk&7)] = (unsigned short)bf16bits(vv_);
  }
}

// ---------------- fused regional+base attention ----------------
// 512 threads (8 waves) per (head, 128-query chunk); one 16-query set per
// wave. K (48KB) staged in LDS; V frags from L2 with pinned register
// prefetch (round 10). ROUND 11: cross-phase software pipeline. The
// remaining per-phase serial chain was {K ds_read latency at phase start}
// + {P write -> immediate read RAW (~150cy)}. Fix: double-buffer P in LDS
// (per-wave 2x2KB) and consume P one phase LATE:
//   iter p: read P(p-1)  (written a full phase ago -> no RAW wait)
//           PV(p-1) MFMAs (cover the K-read latency of SCORES(p))
//           SCORES(p): K reads + MFMA + exp + P-write into buf p&1
//           VLOAD(p)   (pinned; V consumed by PV(p) next iter)
// All buffer indices compile-time. LDS = 48 + 32 = 80KB -> 2 blocks/CU.
__global__ __launch_bounds__(512)
void attn_kernel(const float* __restrict__ q,
                 const unsigned* __restrict__ allowed,
                 const unsigned short* __restrict__ Kb,
                 const unsigned short* __restrict__ VT,
                 float* __restrict__ out){
  const int h    = blockIdx.y;
  const int wave = threadIdx.x >> 6;
  const int lane = threadIdx.x & 63;
  const int c    = lane & 15;        // query col / fragment row
  const int Q    = lane >> 4;        // quad

  __shared__ __align__(16) char Ks[49152];   // 24 tiles x 2 frags x 1KB
  __shared__ __align__(16) char Ps[32768];   // 8 waves x 2 bufs x 2KB

  const int s = blockIdx.x*128 + wave*16 + c;

  // ---- stage K: issue the 6 loads first; q work overlaps the latency
  const char* kg = (const char*)Kb + (size_t)h*49152;
  short8 st0 = *(const short8*)(kg + wave*6144 + 0*1024 + lane*16);
  short8 st1 = *(const short8*)(kg + wave*6144 + 1*1024 + lane*16);
  short8 st2 = *(const short8*)(kg + wave*6144 + 2*1024 + lane*16);
  short8 st3 = *(const short8*)(kg + wave*6144 + 3*1024 + lane*16);
  short8 st4 = *(const short8*)(kg + wave*6144 + 4*1024 + lane*16);
  short8 st5 = *(const short8*)(kg + wave*6144 + 5*1024 + lane*16);

  // ---- q load -> bf16 frags immediately (8 regs live past here)
  const unsigned ab = allowed[s];
  const float* qp = q + ((size_t)s*8 + h)*64 + Q*8;
  f32x4 q0 = *(const f32x4*)(qp);
  f32x4 q1 = *(const f32x4*)(qp+4);
  f32x4 q2 = *(const f32x4*)(qp+32);
  f32x4 q3 = *(const f32x4*)(qp+36);
  short8 f0, f1;
  #pragma unroll
  for (int j=0;j<4;j++){
    f0[j] = bf16bits(q0[j]); f0[4+j] = bf16bits(q1[j]);
    f1[j] = bf16bits(q2[j]); f1[4+j] = bf16bits(q3[j]);
  }

  // ---- K -> LDS (pure linear, conflict-free)
  *(short8*)(Ks + wave*6144 + 0*1024 + lane*16) = st0;
  *(short8*)(Ks + wave*6144 + 1*1024 + lane*16) = st1;
  *(short8*)(Ks + wave*6144 + 2*1024 + lane*16) = st2;
  *(short8*)(Ks + wave*6144 + 3*1024 + lane*16) = st3;
  *(short8*)(Ks + wave*6144 + 4*1024 + lane*16) = st4;
  *(short8*)(Ks + wave*6144 + 5*1024 + lane*16) = st5;

  // ---- identity-lane fragment bases (linear, conflict-free)
  const char* kfb = Ks + lane*16;                                 // + (t*2+f)*1024
  const char* vgf = (const char*)VT + (size_t)h*49152 + lane*16;  // global V frags
  char*       pwb = Ps + wave*4096 + (Q>>1)*256 + c*16 + (Q&1)*8; // + buf*2048 + i*512
  const char* prb = Ps + wave*4096 + lane*16;                     // + buf*2048 + klp*1024

  // ---- V prefetch buffer (single, compile-time indexed)
  short8 v0, v1, v2, v3, v4, v5, v6, v7;
#define VLOAD(ph)                                                     \
  v0 = *(const short8*)(vgf + (((ph)*2+0)*4+0)*1024);                 \
  v1 = *(const short8*)(vgf + (((ph)*2+0)*4+1)*1024);                 \
  v2 = *(const short8*)(vgf + (((ph)*2+0)*4+2)*1024);                 \
  v3 = *(const short8*)(vgf + (((ph)*2+0)*4+3)*1024);                 \
  v4 = *(const short8*)(vgf + (((ph)*2+1)*4+0)*1024);                 \
  v5 = *(const short8*)(vgf + (((ph)*2+1)*4+1)*1024);                 \
  v6 = *(const short8*)(vgf + (((ph)*2+1)*4+2)*1024);                 \
  v7 = *(const short8*)(vgf + (((ph)*2+1)*4+3)*1024);                 \
  __builtin_amdgcn_sched_barrier(0);   /* pin: loads may not sink */

#define DO_SCORES(ph, BUF, LSUM, AM)                                  \
  {                                                                   \
    _Pragma("unroll")                                                 \
    for (int i=0;i<4;i++){                                            \
      const int t = (ph)*4 + i;                                       \
      short8 kf0 = *(const short8*)(kfb + (t*2  )*1024);              \
      short8 kf1 = *(const short8*)(kfb + (t*2+1)*1024);              \
      f32x4 s4 = {0,0,0,0};                                           \
      s4 = MFMA_BF16(kf0,f0,s4); s4 = MFMA_BF16(kf1,f1,s4);           \
      short4v pk;                                                     \
      _Pragma("unroll")                                               \
      for (int r=0;r<4;r++){                                          \
        float e = (AM)*EXP_SCORE(s4[r]); LSUM += e;                   \
        pk[r] = bf16bits(e);                                          \
      }                                                               \
      *(short4v*)(pwb + (BUF)*2048 + i*512) = pk;                     \
    }                                                                 \
  }

// read P of the PREVIOUS phase (no RAW wait) then 8 PV MFMAs
#define DO_PV(BUF, ACC)                                               \
  {                                                                   \
    short8 pf0 = *(const short8*)(prb + (BUF)*2048);                  \
    short8 pf1 = *(const short8*)(prb + (BUF)*2048 + 1024);           \
    ACC[0] = MFMA_BF16(v0, pf0, ACC[0]);                              \
    ACC[1] = MFMA_BF16(v1, pf0, ACC[1]);                              \
    ACC[2] = MFMA_BF16(v2, pf0, ACC[2]);                              \
    ACC[3] = MFMA_BF16(v3, pf0, ACC[3]);                              \
    ACC[0] = MFMA_BF16(v4, pf1, ACC[0]);                              \
    ACC[1] = MFMA_BF16(v5, pf1, ACC[1]);                              \
    ACC[2] = MFMA_BF16(v6, pf1, ACC[2]);                              \
    ACC[3] = MFMA_BF16(v7, pf1, ACC[3]);                              \
  }

  // phase-0 V loads before the barrier: drained alongside K staging, free
  VLOAD(0);

  __syncthreads();   // staged K visible to all waves

  const float am1 = (ab>>1)&1u ? 1.f : 0.f;   // region 0 (phases 2-3)
  const float am2 = (ab>>2)&1u ? 1.f : 0.f;   // region 1 (phases 4-5)

  float lb=0.f, lr=0.f;
  f32x4 a0[4], a1[4];
  #pragma unroll
  for (int m=0;m<4;m++){ a0[m]=(f32x4){0,0,0,0}; a1[m]=(f32x4){0,0,0,0}; }

  // ---- software-pipelined phases: PV runs one phase behind SCORES
  DO_SCORES(0, 0, lb, 1.0f);                                // prologue
  DO_PV(0, a0);  DO_SCORES(1, 1, lb, 1.0f);   VLOAD(1);     // PV(0)
  DO_PV(1, a0);  DO_SCORES(2, 0, lr, am1);    VLOAD(2);     // PV(1)
  DO_PV(0, a1);  DO_SCORES(3, 1, lr, am1);    VLOAD(3);     // PV(2)
  DO_PV(1, a1);  DO_SCORES(4, 0, lr, am2);    VLOAD(4);     // PV(3)
  DO_PV(0, a1);  DO_SCORES(5, 1, lr, am2);    VLOAD(5);     // PV(4)
  DO_PV(1, a1);                                             // PV(5) epilogue

  // ---- row-sum reductions (query lives in lane&15; reduce across quads)
  lb += __shfl_xor(lb,16); lb += __shfl_xor(lb,32);
  lr += __shfl_xor(lr,16); lr += __shfl_xor(lr,32);

  const float invb = 0.5f/lb;
  const float lreg = ((ab&1u)? lb : 0.f) + lr;
  const float invr = 0.5f/lreg;
  const float cA   = invb + ((ab&1u)? invr : 0.f);

  // ---- store: lane holds d = m*16 + Q*4 + r for query s (fp32, 16B)
  float* ob = out + (size_t)s*512 + h*64 + Q*4;
  #pragma unroll
  for (int m=0;m<4;m++){
    f32x4 o;
    #pragma unroll
    for (int r=0;r<4;r++) o[r] = a0[m][r]*cA + a1[m][r]*invr;
    *(f32x4*)(ob + m*16) = o;
  }
}

extern "C" void kernel_launch(void* const* d_in, const int* in_sizes, int n_in,
                              void* d_out, int out_size, void* d_ws, size_t ws_size,
                              hipStream_t stream) {
  const float* q  = (const float*)d_in[0];
  const float* k  = (const float*)d_in[1];
  const float* v  = (const float*)d_in[2];
  const float* rk = (const float*)d_in[3];
  const float* rv = (const float*)d_in[4];
  const float* rm = (const float*)d_in[5];
  float* out = (float*)d_out;

  char* ws = (char*)d_ws;
  unsigned*       allowed = (unsigned*)ws;                           // 56320*4   = 225280 B
  unsigned short* Kb      = (unsigned short*)(ws + 225280);          // 8*3*128*64*2 = 393216 B
  unsigned short* VT      = (unsigned short*)(ws + 225280 + 393216); // 393216 B

  prep_kernel<<<988, 256, 0, stream>>>(rm, k, v, rk, rv, allowed, Kb, VT);
  dim3 grid(440, 8);
  attn_kernel<<<grid, 512, 0, stream>>>(q, allowed, Kb, VT, out);
}